// Round 1
// 117.071 us; speedup vs baseline: 1.0830x; 1.0830x over previous
//
#include <hip/hip_runtime.h>
#include <hip/hip_bf16.h>
#include <stdint.h>

#define NN 128
#define DD 64
#define HH 128

__device__ __forceinline__ float bflo(uint32_t u){ union{uint32_t u;float f;} c; c.u = u<<16; return c.f; }
__device__ __forceinline__ float bfhi(uint32_t u){ union{uint32_t u;float f;} c; c.u = u & 0xffff0000u; return c.f; }
__device__ __forceinline__ uint32_t packbf(float lo, float hi){
  __hip_bfloat16 a = __float2bfloat16(lo);
  __hip_bfloat16 b = __float2bfloat16(hi);
  uint16_t ua = *(uint16_t*)&a, ub = *(uint16_t*)&b;
  return (uint32_t)ua | ((uint32_t)ub<<16);
}

// K1:
//  blocks 0..511   : Pm = x@W1[:64]+b1, Qm = x@W1[64:], Pa = x@A1[:64]+ab1, Qa = x@A1[64:]
//                    Qm/Qa packed bf16 (h,h+64) per dword, layout [b][j][hp] -- coalesced stores
//  blocks 512..640 : M = W2@U1[64:], c0 = b2@U1[64:]+ub1  (update-net precomposition)
__global__ __launch_bounds__(128) void k1_proj(
    const float* __restrict__ x,
    const float* __restrict__ W1, const float* __restrict__ b1,
    const float* __restrict__ A1, const float* __restrict__ ab1,
    const float* __restrict__ W2, const float* __restrict__ b2,
    const float* __restrict__ U1, const float* __restrict__ ub1,
    float* __restrict__ Pm, float* __restrict__ Pa,
    uint32_t* __restrict__ Qmp, uint32_t* __restrict__ Qap,
    float* __restrict__ M, float* __restrict__ c0){
  const int bid = blockIdx.x;
  const int t = threadIdx.x;           // 0..127
  if(bid >= 512){                      // ---- precompose update-net ----
    int hb = bid - 512;                // 0..128
    if(hb < HH){
      float acc = 0.f;
      #pragma unroll 4
      for(int k=0;k<HH;k++) acc += W2[hb*HH+k] * U1[(DD+k)*HH+t];
      M[hb*HH+t] = acc;
    } else {
      float acc = ub1[t];
      #pragma unroll 4
      for(int k=0;k<HH;k++) acc += b2[k] * U1[(DD+k)*HH+t];
      c0[t] = acc;
    }
    return;
  }
  const int g = bid & 15, b = bid >> 4;
  const int jb = g*4;
  __shared__ float xs[8][64];     // rows: jb..jb+3, jb+64..jb+67
  __shared__ float qmS[8][128];
  __shared__ float qaS[8][128];
  {
    int r = t >> 4, d4 = (t & 15)*4;
    int gr = (r<4) ? (jb+r) : (jb + r - 4 + 64);
    *(float4*)&xs[r][d4] = *(const float4*)&x[(b*NN+gr)*DD + d4];
  }
  __syncthreads();
  float pm[8], qm[8], pa[8], qa[8];
  #pragma unroll
  for(int r=0;r<8;r++){ pm[r]=0.f;qm[r]=0.f;pa[r]=0.f;qa[r]=0.f; }
  for(int d0=0; d0<DD; d0+=4){
    float4 xr[8];
    #pragma unroll
    for(int r=0;r<8;r++) xr[r] = *(const float4*)&xs[r][d0];
    #pragma unroll
    for(int dd=0; dd<4; dd++){
      const int d = d0 + dd;
      float w1a = W1[d*HH + t];
      float w1b = W1[(DD+d)*HH + t];
      float a1a = A1[d*HH + t];
      float a1b = A1[(DD+d)*HH + t];
      #pragma unroll
      for(int r=0;r<8;r++){
        float xv = (&xr[r].x)[dd];
        pm[r] += xv*w1a; qm[r] += xv*w1b;
        pa[r] += xv*a1a; qa[r] += xv*a1b;
      }
    }
  }
  float b1v = b1[t], ab1v = ab1[t];
  #pragma unroll
  for(int r=0;r<8;r++){
    int gr = (r<4) ? (jb+r) : (jb + r - 4 + 64);
    Pm[(b*NN+gr)*HH + t] = pm[r] + b1v;
    Pa[(b*NN+gr)*HH + t] = pa[r] + ab1v;
    qmS[r][t] = qm[r];
    qaS[r][t] = qa[r];
  }
  __syncthreads();
  // pack (h, h+64) pairs; coalesced global stores
  #pragma unroll
  for(int k=0;k<4;k++){
    int idx = t + k*128;              // 0..511
    int r = idx >> 6, hp = idx & 63;
    int gr = (r<4) ? (jb+r) : (jb + r - 4 + 64);
    Qmp[(b*NN+gr)*64 + hp] = packbf(qmS[r][hp], qmS[r][hp+64]);
    Qap[(b*NN+gr)*64 + hp] = packbf(qaS[r][hp], qaS[r][hp+64]);
  }
}

// K2 fused: per block = (batch b, 8 i-rows)
//  phase 1: logits_ij = sum_h relu(Pa_i[h]+Qa_j[h])*A2[h]; masked softmax -> atS (LDS)
//  phase 2: hbar_i[h] = sum_j attn_ij * relu(Pm_i[h]+Qm_j[h])  -> kept in LDS (pS reused)
//  phase 3: hidden = relu(x@U1[:64] + hbar@M + c0); out = x + hidden@U2 + ub2
//           hidden reuses atS; U1/M/U2 read from L2 (weights shared by all 512 blocks)
// qbuf rows padded to 65 dwords: bank = (row+col)%32 -> 2-way alias only (free).
__global__ __launch_bounds__(256) void k2_fused(
    const float* __restrict__ Pa, const float* __restrict__ Pm,
    const uint32_t* __restrict__ Qap, const uint32_t* __restrict__ Qmp,
    const float* __restrict__ A2, const int* __restrict__ masks,
    const float* __restrict__ x, const float* __restrict__ M,
    const float* __restrict__ c0,
    const float* __restrict__ U1, const float* __restrict__ U2,
    const float* __restrict__ ub2, float* __restrict__ out){
  const int it = blockIdx.x;     // 0..15 (8 i each)
  const int b  = blockIdx.y;     // 0..31
  const int t = threadIdx.x;     // 0..255
  const int wave = t>>6, lane = t&63;
  __shared__ uint32_t qbuf[NN*65];   // 33.3 KB, padded rows
  __shared__ float pS[8*HH];         // Pa rows, then Pm rows, then hbar
  __shared__ float a2S[HH];
  __shared__ float atS[8*NN];        // attention weights, then hidden
  __shared__ float xs[8][DD];        // x rows for phase 3
  {
    const uint32_t* src = Qap + (size_t)b*NN*64;
    #pragma unroll
    for(int k=0;k<8;k++){
      int idx4 = t + k*256;                  // 0..2047 (uint4 index)
      int j = idx4 >> 4, hp4 = (idx4 & 15)*4;
      uint4 v = *(const uint4*)&src[j*64 + hp4];
      uint32_t* d = &qbuf[j*65 + hp4];
      d[0]=v.x; d[1]=v.y; d[2]=v.z; d[3]=v.w;
    }
    int r = t>>5, h4 = (t&31)*4;
    *(float4*)&pS[r*HH + h4] = *(const float4*)&Pa[(b*NN + it*8 + r)*HH + h4];
    if(t < HH) a2S[t] = A2[t];
    if(t < 128){
      int xr = t >> 4, d4 = (t & 15)*4;
      *(float4*)&xs[xr][d4] = *(const float4*)&x[(b*NN + it*8 + xr)*DD + d4];
    }
  }
  __syncthreads();
  const int i0 = wave*2, i1 = i0+1;
  float a00=0.f,a01=0.f,a10=0.f,a11=0.f;   // (i0,jl),(i0,jh),(i1,jl),(i1,jh)
  for(int h0=0; h0<64; h0+=4){
    float4 p0a = *(const float4*)&pS[i0*HH + h0];
    float4 p0b = *(const float4*)&pS[i0*HH + 64 + h0];
    float4 p1a = *(const float4*)&pS[i1*HH + h0];
    float4 p1b = *(const float4*)&pS[i1*HH + 64 + h0];
    float4 a2a = *(const float4*)&a2S[h0];
    float4 a2b = *(const float4*)&a2S[64 + h0];
    #pragma unroll
    for(int dd=0; dd<4; dd++){
      uint32_t q0 = qbuf[lane*65 + h0 + dd];        // j = lane
      uint32_t q1 = qbuf[(lane+64)*65 + h0 + dd];   // j = lane+64
      float q0l=bflo(q0), q0h=bfhi(q0), q1l=bflo(q1), q1h=bfhi(q1);
      float pa0=(&p0a.x)[dd], pb0=(&p0b.x)[dd];
      float pa1=(&p1a.x)[dd], pb1=(&p1b.x)[dd];
      float aa=(&a2a.x)[dd],  ab=(&a2b.x)[dd];
      a00 += fmaxf(pa0+q0l,0.f)*aa; a00 += fmaxf(pb0+q0h,0.f)*ab;
      a01 += fmaxf(pa0+q1l,0.f)*aa; a01 += fmaxf(pb0+q1h,0.f)*ab;
      a10 += fmaxf(pa1+q0l,0.f)*aa; a10 += fmaxf(pb1+q0h,0.f)*ab;
      a11 += fmaxf(pa1+q1l,0.f)*aa; a11 += fmaxf(pb1+q1h,0.f)*ab;
    }
  }
  const int m0 = masks[b*NN + lane];
  const int m1 = masks[b*NN + 64 + lane];
  const float NEG = -3.0e38f;
  #pragma unroll
  for(int ii=0; ii<2; ii++){
    float x0 = ii ? a10 : a00, x1 = ii ? a11 : a01;
    int il = ii ? i1 : i0;
    float l0 = m0 ? x0 : NEG, l1 = m1 ? x1 : NEG;
    float v = fmaxf(l0, l1);
    for(int off=32; off>=1; off>>=1) v = fmaxf(v, __shfl_xor(v, off));
    float e0 = m0 ? __expf(x0 - v) : 0.f;
    float e1 = m1 ? __expf(x1 - v) : 0.f;
    float s = e0 + e1;
    for(int off=32; off>=1; off>>=1) s += __shfl_xor(s, off);
    float inv = (s > 0.f) ? (1.f/s) : 0.f;
    atS[il*NN + lane]      = e0*inv;
    atS[il*NN + 64 + lane] = e1*inv;
  }
  __syncthreads();   // phase-1 reads of qbuf/pS complete; atS visible
  {
    const uint32_t* src = Qmp + (size_t)b*NN*64;
    #pragma unroll
    for(int k=0;k<8;k++){
      int idx4 = t + k*256;
      int j = idx4 >> 4, hp4 = (idx4 & 15)*4;
      uint4 v = *(const uint4*)&src[j*64 + hp4];
      uint32_t* d = &qbuf[j*65 + hp4];
      d[0]=v.x; d[1]=v.y; d[2]=v.z; d[3]=v.w;
    }
    int r = t>>5, h4 = (t&31)*4;
    *(float4*)&pS[r*HH + h4] = *(const float4*)&Pm[(b*NN + it*8 + r)*HH + h4];
  }
  __syncthreads();
  float pm00 = pS[i0*HH + lane], pm01 = pS[i0*HH + 64 + lane];
  float pm10 = pS[i1*HH + lane], pm11 = pS[i1*HH + 64 + lane];
  float h00=0.f,h01=0.f,h10=0.f,h11=0.f;
  for(int j0=0; j0<NN; j0+=4){
    float4 at0 = *(const float4*)&atS[i0*NN + j0];
    float4 at1 = *(const float4*)&atS[i1*NN + j0];
    #pragma unroll
    for(int dd=0; dd<4; dd++){
      uint32_t qd = qbuf[(j0+dd)*65 + lane];   // h = lane / lane+64
      float ql = bflo(qd), qh = bfhi(qd);
      float w0 = (&at0.x)[dd], w1 = (&at1.x)[dd];
      h00 += w0*fmaxf(pm00+ql,0.f);
      h01 += w0*fmaxf(pm01+qh,0.f);
      h10 += w1*fmaxf(pm10+ql,0.f);
      h11 += w1*fmaxf(pm11+qh,0.f);
    }
  }
  // ---- phase 3: update-net, fused (was K3) ----
  __syncthreads();                    // everyone done reading pS (pm regs) & atS
  pS[i0*HH + lane]      = h00;        // hbar -> pS (reuse)
  pS[i0*HH + 64 + lane] = h01;
  pS[i1*HH + lane]      = h10;
  pS[i1*HH + 64 + lane] = h11;
  __syncthreads();
  {
    // hidden[r][c] = relu( sum_d x[r][d]*U1[d][c] + sum_h hbar[r][h]*M[h][c] + c0[c] )
    const int c = t & 127, gg = t >> 7;   // 2 groups x 4 rows
    float acc[4];
    #pragma unroll
    for(int r=0;r<4;r++) acc[r]=0.f;
    for(int d0=0; d0<DD; d0+=4){
      float u0 = U1[(d0+0)*HH + c];
      float u1 = U1[(d0+1)*HH + c];
      float u2 = U1[(d0+2)*HH + c];
      float u3 = U1[(d0+3)*HH + c];
      #pragma unroll
      for(int r=0;r<4;r++){
        float4 xv = *(const float4*)&xs[gg*4+r][d0];     // LDS broadcast
        acc[r] += xv.x*u0 + xv.y*u1 + xv.z*u2 + xv.w*u3;
      }
    }
    for(int h0=0; h0<HH; h0+=4){
      float m0v = M[(h0+0)*HH + c];
      float m1v = M[(h0+1)*HH + c];
      float m2v = M[(h0+2)*HH + c];
      float m3v = M[(h0+3)*HH + c];
      #pragma unroll
      for(int r=0;r<4;r++){
        float4 hv = *(const float4*)&pS[(gg*4+r)*HH + h0];  // LDS broadcast
        acc[r] += hv.x*m0v + hv.y*m1v + hv.z*m2v + hv.w*m3v;
      }
    }
    float cc = c0[c];
    #pragma unroll
    for(int r=0;r<4;r++) atS[(gg*4+r)*NN + c] = fmaxf(acc[r]+cc, 0.f);  // hidden -> atS (reuse)
  }
  __syncthreads();
  {
    // out[r][d] = x[r][d] + sum_c hidden[r][c]*U2[c][d] + ub2[d]
    const int dcol = t & 63, rg = t >> 6;   // 4 groups x 2 rows
    float acc2[2];
    acc2[0]=0.f; acc2[1]=0.f;
    for(int ci=0; ci<HH; ci+=4){
      float u20 = U2[(ci+0)*DD + dcol];
      float u21 = U2[(ci+1)*DD + dcol];
      float u22 = U2[(ci+2)*DD + dcol];
      float u23 = U2[(ci+3)*DD + dcol];
      #pragma unroll
      for(int r=0;r<2;r++){
        float4 hv = *(const float4*)&atS[(rg*2+r)*NN + ci];  // LDS broadcast
        acc2[r] += hv.x*u20 + hv.y*u21 + hv.z*u22 + hv.w*u23;
      }
    }
    float ub = ub2[dcol];
    #pragma unroll
    for(int r=0;r<2;r++){
      int grow = b*NN + it*8 + rg*2 + r;
      out[grow*DD + dcol] = xs[rg*2+r][dcol] + acc2[r] + ub;
    }
  }
}

extern "C" void kernel_launch(void* const* d_in, const int* in_sizes, int n_in,
                              void* d_out, int out_size, void* d_ws, size_t ws_size,
                              hipStream_t stream){
  const float* x   = (const float*)d_in[0];
  const int*   msk = (const int*)d_in[1];
  const float* W1  = (const float*)d_in[2];
  const float* b1  = (const float*)d_in[3];
  const float* W2  = (const float*)d_in[4];
  const float* b2  = (const float*)d_in[5];
  const float* A1  = (const float*)d_in[6];
  const float* ab1 = (const float*)d_in[7];
  const float* A2  = (const float*)d_in[8];
  // d_in[9] = ab2: additive constant on logits, softmax-invariant -> unused
  const float* U1  = (const float*)d_in[10];
  const float* ub1 = (const float*)d_in[11];
  const float* U2  = (const float*)d_in[12];
  const float* ub2 = (const float*)d_in[13];
  float* out = (float*)d_out;

  char* w = (char*)d_ws;
  float*    Pm   = (float*)(w);                        // 2 MB
  float*    Pa   = (float*)(w + (2u<<20));             // 2 MB
  uint32_t* Qmp  = (uint32_t*)(w + (4u<<20));          // 1 MB packed bf16 pairs
  uint32_t* Qap  = (uint32_t*)(w + (5u<<20));          // 1 MB
  float*    M    = (float*)(w + (8u<<20));             // 64 KB
  float*    c0   = (float*)(w + (8u<<20) + (64u<<10)); // 512 B

  hipLaunchKernelGGL(k1_proj, dim3(641), dim3(128), 0, stream,
                     x, W1, b1, A1, ab1, W2, b2, U1, ub1,
                     Pm, Pa, Qmp, Qap, M, c0);
  hipLaunchKernelGGL(k2_fused, dim3(16,32), dim3(256), 0, stream,
                     Pa, Pm, Qap, Qmp, A2, msk, x, M, c0, U1, U2, ub2, out);
}

// Round 2
// 116.403 us; speedup vs baseline: 1.0892x; 1.0057x over previous
//
#include <hip/hip_runtime.h>
#include <hip/hip_bf16.h>
#include <stdint.h>

#define NN 128
#define DD 64
#define HH 128

__device__ __forceinline__ float bflo(uint32_t u){ union{uint32_t u;float f;} c; c.u = u<<16; return c.f; }
__device__ __forceinline__ float bfhi(uint32_t u){ union{uint32_t u;float f;} c; c.u = u & 0xffff0000u; return c.f; }
__device__ __forceinline__ uint32_t packbf(float lo, float hi){
  __hip_bfloat16 a = __float2bfloat16(lo);
  __hip_bfloat16 b = __float2bfloat16(hi);
  uint16_t ua = *(uint16_t*)&a, ub = *(uint16_t*)&b;
  return (uint32_t)ua | ((uint32_t)ub<<16);
}

// K1:
//  blocks 0..511   : Pm = x@W1[:64]+b1, Qm = x@W1[64:], Pa = x@A1[:64]+ab1, Qa = x@A1[64:]
//                    Qm/Qa packed bf16 (h,h+64) per dword, layout [b][j][hp] -- coalesced stores
//  blocks 512..640 : M = W2@U1[64:], c0 = b2@U1[64:]+ub1  (update-net precomposition)
__global__ __launch_bounds__(128) void k1_proj(
    const float* __restrict__ x,
    const float* __restrict__ W1, const float* __restrict__ b1,
    const float* __restrict__ A1, const float* __restrict__ ab1,
    const float* __restrict__ W2, const float* __restrict__ b2,
    const float* __restrict__ U1, const float* __restrict__ ub1,
    float* __restrict__ Pm, float* __restrict__ Pa,
    uint32_t* __restrict__ Qmp, uint32_t* __restrict__ Qap,
    float* __restrict__ M, float* __restrict__ c0){
  const int bid = blockIdx.x;
  const int t = threadIdx.x;           // 0..127
  if(bid >= 512){                      // ---- precompose update-net ----
    int hb = bid - 512;                // 0..128
    if(hb < HH){
      float acc = 0.f;
      #pragma unroll 4
      for(int k=0;k<HH;k++) acc += W2[hb*HH+k] * U1[(DD+k)*HH+t];
      M[hb*HH+t] = acc;
    } else {
      float acc = ub1[t];
      #pragma unroll 4
      for(int k=0;k<HH;k++) acc += b2[k] * U1[(DD+k)*HH+t];
      c0[t] = acc;
    }
    return;
  }
  const int g = bid & 15, b = bid >> 4;
  const int jb = g*4;
  __shared__ float xs[8][64];     // rows: jb..jb+3, jb+64..jb+67
  __shared__ float qmS[8][128];
  __shared__ float qaS[8][128];
  {
    int r = t >> 4, d4 = (t & 15)*4;
    int gr = (r<4) ? (jb+r) : (jb + r - 4 + 64);
    *(float4*)&xs[r][d4] = *(const float4*)&x[(b*NN+gr)*DD + d4];
  }
  __syncthreads();
  float pm[8], qm[8], pa[8], qa[8];
  #pragma unroll
  for(int r=0;r<8;r++){ pm[r]=0.f;qm[r]=0.f;pa[r]=0.f;qa[r]=0.f; }
  for(int d0=0; d0<DD; d0+=4){
    float4 xr[8];
    #pragma unroll
    for(int r=0;r<8;r++) xr[r] = *(const float4*)&xs[r][d0];
    #pragma unroll
    for(int dd=0; dd<4; dd++){
      const int d = d0 + dd;
      float w1a = W1[d*HH + t];
      float w1b = W1[(DD+d)*HH + t];
      float a1a = A1[d*HH + t];
      float a1b = A1[(DD+d)*HH + t];
      #pragma unroll
      for(int r=0;r<8;r++){
        float xv = (&xr[r].x)[dd];
        pm[r] += xv*w1a; qm[r] += xv*w1b;
        pa[r] += xv*a1a; qa[r] += xv*a1b;
      }
    }
  }
  float b1v = b1[t], ab1v = ab1[t];
  #pragma unroll
  for(int r=0;r<8;r++){
    int gr = (r<4) ? (jb+r) : (jb + r - 4 + 64);
    Pm[(b*NN+gr)*HH + t] = pm[r] + b1v;
    Pa[(b*NN+gr)*HH + t] = pa[r] + ab1v;
    qmS[r][t] = qm[r];
    qaS[r][t] = qa[r];
  }
  __syncthreads();
  // pack (h, h+64) pairs; coalesced global stores
  #pragma unroll
  for(int k=0;k<4;k++){
    int idx = t + k*128;              // 0..511
    int r = idx >> 6, hp = idx & 63;
    int gr = (r<4) ? (jb+r) : (jb + r - 4 + 64);
    Qmp[(b*NN+gr)*64 + hp] = packbf(qmS[r][hp], qmS[r][hp+64]);
    Qap[(b*NN+gr)*64 + hp] = packbf(qaS[r][hp], qaS[r][hp+64]);
  }
}

// K2 fused, mask-compacted: per block = (batch b, 8 i-rows)
//  compaction: valid j list (jlS, cnt) via per-wave ballot+popc prefix; ~half of j are masked out
//  phase 1: logits over COMPACTED j only; high half (jc>=64) skipped when cnt<=64
//  phase 2: hbar over compacted j (cnt4 trip count instead of 128)
//  phase 3: hidden = relu(x@U1[:64] + hbar@M + c0); out = x + hidden@U2 + ub2
// Exactness: removed j-terms contributed exact zeros sequentially; compacted order stays
// ascending-j, so FP partial-sum order is unchanged vs the uncompacted kernel.
// qbuf rows padded to 65 dwords: bank = (row+col)%32 -> 2-way alias only (free).
__global__ __launch_bounds__(256) void k2_fused(
    const float* __restrict__ Pa, const float* __restrict__ Pm,
    const uint32_t* __restrict__ Qap, const uint32_t* __restrict__ Qmp,
    const float* __restrict__ A2, const int* __restrict__ masks,
    const float* __restrict__ x, const float* __restrict__ M,
    const float* __restrict__ c0,
    const float* __restrict__ U1, const float* __restrict__ U2,
    const float* __restrict__ ub2, float* __restrict__ out){
  const int it = blockIdx.x;     // 0..15 (8 i each)
  const int b  = blockIdx.y;     // 0..31
  const int t = threadIdx.x;     // 0..255
  const int wave = t>>6, lane = t&63;
  __shared__ uint32_t qbuf[NN*65];   // 33.3 KB, padded rows (compacted j rows)
  __shared__ float pS[8*HH];         // Pa rows, then Pm rows, then hbar
  __shared__ float a2S[HH];
  __shared__ float atS[8*NN];        // attention weights (compacted), then hidden
  __shared__ float xs[8][DD];        // x rows for phase 3
  __shared__ unsigned long long balS[2];
  __shared__ int jlS[NN];            // compacted valid-j list
  // ---- mask ballot (waves 0,1 cover j=0..127) + independent staging ----
  int mym = 0;
  if(t < 128) mym = masks[b*NN + t];
  {
    unsigned long long bal = __ballot(mym != 0);
    if(wave < 2 && lane == 0) balS[wave] = bal;
  }
  {
    int r = t>>5, h4 = (t&31)*4;
    *(float4*)&pS[r*HH + h4] = *(const float4*)&Pa[(b*NN + it*8 + r)*HH + h4];
    if(t < HH) a2S[t] = A2[t];
    if(t < 128){
      int xr = t >> 4, d4 = (t & 15)*4;
      *(float4*)&xs[xr][d4] = *(const float4*)&x[(b*NN + it*8 + xr)*DD + d4];
    }
  }
  __syncthreads();
  const int cnt0 = __popcll(balS[0]);
  const int cnt  = cnt0 + __popcll(balS[1]);
  const int cnt4 = (cnt + 3) & ~3;
  if(t < 128 && mym){
    unsigned long long bw = balS[wave];
    int pos = __popcll(bw & ((1ull<<lane)-1)) + (wave ? cnt0 : 0);
    jlS[pos] = t;
  }
  __syncthreads();
  // ---- stage Qap compacted (zero-pad rows cnt..cnt4) ----
  {
    const uint32_t* src = Qap + (size_t)b*NN*64;
    for(int idx4 = t; idx4 < cnt4*16; idx4 += 256){
      int j = idx4 >> 4, hp4 = (idx4 & 15)*4;
      uint4 v = make_uint4(0u,0u,0u,0u);
      if(j < cnt) v = *(const uint4*)&src[jlS[j]*64 + hp4];
      uint32_t* d = &qbuf[j*65 + hp4];
      d[0]=v.x; d[1]=v.y; d[2]=v.z; d[3]=v.w;
    }
  }
  __syncthreads();
  const int i0 = wave*2, i1 = i0+1;
  const bool hasHi = (cnt > 64);
  float a00=0.f,a01=0.f,a10=0.f,a11=0.f;   // (i0,jcL),(i0,jcH),(i1,jcL),(i1,jcH)
  for(int h0=0; h0<64; h0+=4){
    float4 p0a = *(const float4*)&pS[i0*HH + h0];
    float4 p0b = *(const float4*)&pS[i0*HH + 64 + h0];
    float4 p1a = *(const float4*)&pS[i1*HH + h0];
    float4 p1b = *(const float4*)&pS[i1*HH + 64 + h0];
    float4 a2a = *(const float4*)&a2S[h0];
    float4 a2b = *(const float4*)&a2S[64 + h0];
    #pragma unroll
    for(int dd=0; dd<4; dd++){
      uint32_t q0 = qbuf[lane*65 + h0 + dd];        // jc = lane
      float q0l=bflo(q0), q0h=bfhi(q0);
      float pa0=(&p0a.x)[dd], pb0=(&p0b.x)[dd];
      float pa1=(&p1a.x)[dd], pb1=(&p1b.x)[dd];
      float aa=(&a2a.x)[dd],  ab=(&a2b.x)[dd];
      a00 += fmaxf(pa0+q0l,0.f)*aa; a00 += fmaxf(pb0+q0h,0.f)*ab;
      a10 += fmaxf(pa1+q0l,0.f)*aa; a10 += fmaxf(pb1+q0h,0.f)*ab;
    }
    if(hasHi){
      #pragma unroll
      for(int dd=0; dd<4; dd++){
        uint32_t q1 = qbuf[(lane+64)*65 + h0 + dd];   // jc = lane+64
        float q1l=bflo(q1), q1h=bfhi(q1);
        float pa0=(&p0a.x)[dd], pb0=(&p0b.x)[dd];
        float pa1=(&p1a.x)[dd], pb1=(&p1b.x)[dd];
        float aa=(&a2a.x)[dd],  ab=(&a2b.x)[dd];
        a01 += fmaxf(pa0+q1l,0.f)*aa; a01 += fmaxf(pb0+q1h,0.f)*ab;
        a11 += fmaxf(pa1+q1l,0.f)*aa; a11 += fmaxf(pb1+q1h,0.f)*ab;
      }
    }
  }
  const bool v0c = (lane < cnt);
  const bool v1c = (lane + 64 < cnt);
  const float NEG = -3.0e38f;
  #pragma unroll
  for(int ii=0; ii<2; ii++){
    float x0 = ii ? a10 : a00, x1 = ii ? a11 : a01;
    int il = ii ? i1 : i0;
    float l0 = v0c ? x0 : NEG, l1 = v1c ? x1 : NEG;
    float v = fmaxf(l0, l1);
    for(int off=32; off>=1; off>>=1) v = fmaxf(v, __shfl_xor(v, off));
    float e0 = v0c ? __expf(x0 - v) : 0.f;
    float e1 = v1c ? __expf(x1 - v) : 0.f;
    float s = e0 + e1;
    for(int off=32; off>=1; off>>=1) s += __shfl_xor(s, off);
    float inv = (s > 0.f) ? (1.f/s) : 0.f;
    atS[il*NN + lane]      = e0*inv;
    atS[il*NN + 64 + lane] = e1*inv;
  }
  __syncthreads();   // phase-1 reads of qbuf/pS complete; atS visible
  {
    const uint32_t* src = Qmp + (size_t)b*NN*64;
    for(int idx4 = t; idx4 < cnt4*16; idx4 += 256){
      int j = idx4 >> 4, hp4 = (idx4 & 15)*4;
      uint4 v = make_uint4(0u,0u,0u,0u);
      if(j < cnt) v = *(const uint4*)&src[jlS[j]*64 + hp4];
      uint32_t* d = &qbuf[j*65 + hp4];
      d[0]=v.x; d[1]=v.y; d[2]=v.z; d[3]=v.w;
    }
    int r = t>>5, h4 = (t&31)*4;
    *(float4*)&pS[r*HH + h4] = *(const float4*)&Pm[(b*NN + it*8 + r)*HH + h4];
  }
  __syncthreads();
  float pm00 = pS[i0*HH + lane], pm01 = pS[i0*HH + 64 + lane];
  float pm10 = pS[i1*HH + lane], pm11 = pS[i1*HH + 64 + lane];
  float h00=0.f,h01=0.f,h10=0.f,h11=0.f;
  for(int j0=0; j0<cnt4; j0+=4){
    float4 at0 = *(const float4*)&atS[i0*NN + j0];
    float4 at1 = *(const float4*)&atS[i1*NN + j0];
    #pragma unroll
    for(int dd=0; dd<4; dd++){
      uint32_t qd = qbuf[(j0+dd)*65 + lane];   // h = lane / lane+64
      float ql = bflo(qd), qh = bfhi(qd);
      float w0 = (&at0.x)[dd], w1 = (&at1.x)[dd];
      h00 += w0*fmaxf(pm00+ql,0.f);
      h01 += w0*fmaxf(pm01+qh,0.f);
      h10 += w1*fmaxf(pm10+ql,0.f);
      h11 += w1*fmaxf(pm11+qh,0.f);
    }
  }
  // ---- phase 3: update-net, fused ----
  __syncthreads();                    // everyone done reading pS (pm regs) & atS
  pS[i0*HH + lane]      = h00;        // hbar -> pS (reuse)
  pS[i0*HH + 64 + lane] = h01;
  pS[i1*HH + lane]      = h10;
  pS[i1*HH + 64 + lane] = h11;
  __syncthreads();
  {
    // hidden[r][c] = relu( sum_d x[r][d]*U1[d][c] + sum_h hbar[r][h]*M[h][c] + c0[c] )
    const int c = t & 127, gg = t >> 7;   // 2 groups x 4 rows
    float acc[4];
    #pragma unroll
    for(int r=0;r<4;r++) acc[r]=0.f;
    for(int d0=0; d0<DD; d0+=4){
      float u0 = U1[(d0+0)*HH + c];
      float u1 = U1[(d0+1)*HH + c];
      float u2 = U1[(d0+2)*HH + c];
      float u3 = U1[(d0+3)*HH + c];
      #pragma unroll
      for(int r=0;r<4;r++){
        float4 xv = *(const float4*)&xs[gg*4+r][d0];     // LDS broadcast
        acc[r] += xv.x*u0 + xv.y*u1 + xv.z*u2 + xv.w*u3;
      }
    }
    for(int h0=0; h0<HH; h0+=4){
      float m0v = M[(h0+0)*HH + c];
      float m1v = M[(h0+1)*HH + c];
      float m2v = M[(h0+2)*HH + c];
      float m3v = M[(h0+3)*HH + c];
      #pragma unroll
      for(int r=0;r<4;r++){
        float4 hv = *(const float4*)&pS[(gg*4+r)*HH + h0];  // LDS broadcast
        acc[r] += hv.x*m0v + hv.y*m1v + hv.z*m2v + hv.w*m3v;
      }
    }
    float cc = c0[c];
    #pragma unroll
    for(int r=0;r<4;r++) atS[(gg*4+r)*NN + c] = fmaxf(acc[r]+cc, 0.f);  // hidden -> atS (reuse)
  }
  __syncthreads();
  {
    // out[r][d] = x[r][d] + sum_c hidden[r][c]*U2[c][d] + ub2[d]
    const int dcol = t & 63, rg = t >> 6;   // 4 groups x 2 rows
    float acc2[2];
    acc2[0]=0.f; acc2[1]=0.f;
    for(int ci=0; ci<HH; ci+=4){
      float u20 = U2[(ci+0)*DD + dcol];
      float u21 = U2[(ci+1)*DD + dcol];
      float u22 = U2[(ci+2)*DD + dcol];
      float u23 = U2[(ci+3)*DD + dcol];
      #pragma unroll
      for(int r=0;r<2;r++){
        float4 hv = *(const float4*)&atS[(rg*2+r)*NN + ci];  // LDS broadcast
        acc2[r] += hv.x*u20 + hv.y*u21 + hv.z*u22 + hv.w*u23;
      }
    }
    float ub = ub2[dcol];
    #pragma unroll
    for(int r=0;r<2;r++){
      int grow = b*NN + it*8 + rg*2 + r;
      out[grow*DD + dcol] = xs[rg*2+r][dcol] + acc2[r] + ub;
    }
  }
}

extern "C" void kernel_launch(void* const* d_in, const int* in_sizes, int n_in,
                              void* d_out, int out_size, void* d_ws, size_t ws_size,
                              hipStream_t stream){
  const float* x   = (const float*)d_in[0];
  const int*   msk = (const int*)d_in[1];
  const float* W1  = (const float*)d_in[2];
  const float* b1  = (const float*)d_in[3];
  const float* W2  = (const float*)d_in[4];
  const float* b2  = (const float*)d_in[5];
  const float* A1  = (const float*)d_in[6];
  const float* ab1 = (const float*)d_in[7];
  const float* A2  = (const float*)d_in[8];
  // d_in[9] = ab2: additive constant on logits, softmax-invariant -> unused
  const float* U1  = (const float*)d_in[10];
  const float* ub1 = (const float*)d_in[11];
  const float* U2  = (const float*)d_in[12];
  const float* ub2 = (const float*)d_in[13];
  float* out = (float*)d_out;

  char* w = (char*)d_ws;
  float*    Pm   = (float*)(w);                        // 2 MB
  float*    Pa   = (float*)(w + (2u<<20));             // 2 MB
  uint32_t* Qmp  = (uint32_t*)(w + (4u<<20));          // 1 MB packed bf16 pairs
  uint32_t* Qap  = (uint32_t*)(w + (5u<<20));          // 1 MB
  float*    M    = (float*)(w + (8u<<20));             // 64 KB
  float*    c0   = (float*)(w + (8u<<20) + (64u<<10)); // 512 B

  hipLaunchKernelGGL(k1_proj, dim3(641), dim3(128), 0, stream,
                     x, W1, b1, A1, ab1, W2, b2, U1, ub1,
                     Pm, Pa, Qmp, Qap, M, c0);
  hipLaunchKernelGGL(k2_fused, dim3(16,32), dim3(256), 0, stream,
                     Pa, Pm, Qap, Qmp, A2, msk, x, M, c0, U1, U2, ub2, out);
}